// Round 1
// baseline (226.662 us; speedup 1.0000x reference)
//
#include <hip/hip_runtime.h>

#define TPB 256
#define BPB 16   // blocks per batch -> 64*16 = 1024 blocks = 4 per CU

// Kernel 1: per-batch 4x4x4 histogram with histogramdd range semantics.
// counts[b*64 + flat] accumulates exact integer point counts (uint32).
__global__ __launch_bounds__(TPB) void hist_kernel(const float* __restrict__ x,
                                                   unsigned* __restrict__ counts,
                                                   int N) {
    __shared__ unsigned h[64];
    if (threadIdx.x < 64) h[threadIdx.x] = 0u;
    __syncthreads();

    const int b = blockIdx.y;
    const float* xb = x + (size_t)b * (size_t)N * 3u;
    const int chunk = (N + gridDim.x - 1) / gridDim.x;
    const int start = blockIdx.x * chunk;
    const int end   = min(N, start + chunk);

    for (int i = start + (int)threadIdx.x; i < end; i += TPB) {
        const float x0 = xb[3 * i + 0];
        const float x1 = xb[3 * i + 1];
        const float x2 = xb[3 * i + 2];
        // histogramdd: drop points outside [-2, 2] on any dim; x == 2.0 goes
        // into the last bin (handled by the clip below).
        const bool inside = (x0 >= -2.0f) & (x0 <= 2.0f) &
                            (x1 >= -2.0f) & (x1 <= 2.0f) &
                            (x2 >= -2.0f) & (x2 <= 2.0f);
        const int i0 = min(3, max(0, (int)floorf(x0 + 2.0f)));
        const int i1 = min(3, max(0, (int)floorf(x1 + 2.0f)));
        const int i2 = min(3, max(0, (int)floorf(x2 + 2.0f)));
        if (inside) atomicAdd(&h[(i0 << 4) | (i1 << 2) | i2], 1u);
    }
    __syncthreads();

    if (threadIdx.x < 64) {
        const unsigned v = h[threadIdx.x];
        if (v) atomicAdd(&counts[b * 64 + threadIdx.x], v);
    }
}

// Kernel 2: normalize + Linear(V=64 -> CLASSES=40).
// total in-range points per batch == sum of the 64 bins (inside weight is 1).
__global__ __launch_bounds__(64) void linear_kernel(const unsigned* __restrict__ counts,
                                                    const float* __restrict__ W,
                                                    const float* __restrict__ bias,
                                                    float* __restrict__ out) {
    const int b = blockIdx.x;
    __shared__ float cnt[64];
    cnt[threadIdx.x] = (float)counts[b * 64 + threadIdx.x];
    __syncthreads();

    const int c = threadIdx.x;
    if (c < 40) {
        float acc = 0.0f, tot = 0.0f;
        #pragma unroll
        for (int v = 0; v < 64; ++v) {
            const float cv = cnt[v];
            tot += cv;
            acc = fmaf(cv, W[c * 64 + v], acc);
        }
        out[b * 40 + c] = acc / tot + bias[c];
    }
}

extern "C" void kernel_launch(void* const* d_in, const int* in_sizes, int n_in,
                              void* d_out, int out_size, void* d_ws, size_t ws_size,
                              hipStream_t stream) {
    const float* x    = (const float*)d_in[0];   // [B, N, 3] fp32
    const float* W    = (const float*)d_in[1];   // [40, 64] fp32
    const float* bias = (const float*)d_in[2];   // [40] fp32
    float* out = (float*)d_out;                  // [64, 40] fp32

    const int B = 64;
    const int N = in_sizes[0] / (B * 3);         // 200000

    unsigned* counts = (unsigned*)d_ws;          // B*64 uint32 = 16 KB
    hipMemsetAsync(counts, 0, (size_t)B * 64 * sizeof(unsigned), stream);

    dim3 grid(BPB, B);
    hist_kernel<<<grid, TPB, 0, stream>>>(x, counts, N);
    linear_kernel<<<B, 64, 0, stream>>>(counts, W, bias, out);
}

// Round 3
// 222.119 us; speedup vs baseline: 1.0204x; 1.0204x over previous
//
#include <hip/hip_runtime.h>

#define TPB 256
#define BPB 32   // blocks per batch -> 64*32 = 2048 blocks = 8 per CU = 8 waves/SIMD

typedef float floatx4 __attribute__((ext_vector_type(4)));  // native vector: OK for nontemporal builtins

// Kernel 1: per-batch 4x4x4 histogram with histogramdd range semantics.
// Each thread processes 4 points per iteration via 3x float4 loads (48 B/lane,
// 3 independent loads in flight) for memory-latency hiding.
__global__ __launch_bounds__(TPB) void hist_kernel(const float* __restrict__ x,
                                                   unsigned* __restrict__ counts,
                                                   int Q,   // N/4 quads
                                                   int N) {
    __shared__ unsigned h[64];
    if (threadIdx.x < 64) h[threadIdx.x] = 0u;
    __syncthreads();

    const int b = blockIdx.y;
    const float* xb = x + (size_t)b * (size_t)N * 3u;
    const floatx4* xq = (const floatx4*)xb;   // batch base is 16B-aligned (N*3*4 % 16 == 0)

    auto process = [&](float a, float bb, float c) {
        // histogramdd: drop points outside [-2,2] on any dim; x == 2.0 exactly
        // falls in the last bin (clamp below handles it).
        const bool inside = (fabsf(a) <= 2.0f) & (fabsf(bb) <= 2.0f) & (fabsf(c) <= 2.0f);
        const int i0 = (int)fminf(fmaxf(floorf(a  + 2.0f), 0.0f), 3.0f);
        const int i1 = (int)fminf(fmaxf(floorf(bb + 2.0f), 0.0f), 3.0f);
        const int i2 = (int)fminf(fmaxf(floorf(c  + 2.0f), 0.0f), 3.0f);
        if (inside) atomicAdd(&h[(i0 << 4) | (i1 << 2) | i2], 1u);
    };

    const int stride = gridDim.x * TPB;
    for (int q = blockIdx.x * TPB + (int)threadIdx.x; q < Q; q += stride) {
        const floatx4 p0 = __builtin_nontemporal_load(&xq[3 * q + 0]);
        const floatx4 p1 = __builtin_nontemporal_load(&xq[3 * q + 1]);
        const floatx4 p2 = __builtin_nontemporal_load(&xq[3 * q + 2]);
        process(p0.x, p0.y, p0.z);
        process(p0.w, p1.x, p1.y);
        process(p1.z, p1.w, p2.x);
        process(p2.y, p2.z, p2.w);
    }

    // Tail points (N not divisible by 4): handled by block x==0 only.
    if (blockIdx.x == 0) {
        for (int i = 4 * Q + (int)threadIdx.x; i < N; i += TPB) {
            process(xb[3 * i], xb[3 * i + 1], xb[3 * i + 2]);
        }
    }
    __syncthreads();

    if (threadIdx.x < 64) {
        const unsigned v = h[threadIdx.x];
        if (v) atomicAdd(&counts[b * 64 + threadIdx.x], v);
    }
}

// Kernel 2: normalize + Linear(V=64 -> CLASSES=40).
// total in-range points per batch == sum of the 64 bins (inside weight is 1).
__global__ __launch_bounds__(64) void linear_kernel(const unsigned* __restrict__ counts,
                                                    const float* __restrict__ W,
                                                    const float* __restrict__ bias,
                                                    float* __restrict__ out) {
    const int b = blockIdx.x;
    __shared__ float cnt[64];
    cnt[threadIdx.x] = (float)counts[b * 64 + threadIdx.x];
    __syncthreads();

    const int c = threadIdx.x;
    if (c < 40) {
        float acc = 0.0f, tot = 0.0f;
        #pragma unroll
        for (int v = 0; v < 64; ++v) {
            const float cv = cnt[v];
            tot += cv;
            acc = fmaf(cv, W[c * 64 + v], acc);
        }
        out[b * 40 + c] = acc / tot + bias[c];
    }
}

extern "C" void kernel_launch(void* const* d_in, const int* in_sizes, int n_in,
                              void* d_out, int out_size, void* d_ws, size_t ws_size,
                              hipStream_t stream) {
    const float* x    = (const float*)d_in[0];   // [B, N, 3] fp32
    const float* W    = (const float*)d_in[1];   // [40, 64] fp32
    const float* bias = (const float*)d_in[2];   // [40] fp32
    float* out = (float*)d_out;                  // [64, 40] fp32

    const int B = 64;
    const int N = in_sizes[0] / (B * 3);         // 200000
    const int Q = N / 4;

    unsigned* counts = (unsigned*)d_ws;          // B*64 uint32 = 16 KB
    (void)hipMemsetAsync(counts, 0, (size_t)B * 64 * sizeof(unsigned), stream);

    dim3 grid(BPB, B);
    hist_kernel<<<grid, TPB, 0, stream>>>(x, counts, Q, N);
    linear_kernel<<<B, 64, 0, stream>>>(counts, W, bias, out);
}

// Round 4
// 220.245 us; speedup vs baseline: 1.0291x; 1.0085x over previous
//
#include <hip/hip_runtime.h>

#define TPB 256
#define BPB 32   // blocks per batch -> 64*32 = 2048 blocks = 8 per CU = 8 waves/SIMD

typedef float floatx4 __attribute__((ext_vector_type(4)));

// Kernel 1: per-batch 4x4x4 histogram, histogramdd range semantics.
// Each block writes its OWN 64-bin partial (full overwrite -> no init needed,
// no global atomics). 4 points/thread/iter via 3x float4 loads.
__global__ __launch_bounds__(TPB) void hist_kernel(const float* __restrict__ x,
                                                   unsigned* __restrict__ partials,
                                                   int Q,   // N/4 quads
                                                   int N) {
    __shared__ unsigned h[64];
    if (threadIdx.x < 64) h[threadIdx.x] = 0u;
    __syncthreads();

    const int b = blockIdx.y;
    const float* xb = x + (size_t)b * (size_t)N * 3u;
    const floatx4* xq = (const floatx4*)xb;   // batch base is 16B-aligned

    auto process = [&](float a, float bb, float c) {
        // drop points outside [-2,2] on any dim; x == 2.0 exactly -> last bin
        const bool inside = (fabsf(a) <= 2.0f) & (fabsf(bb) <= 2.0f) & (fabsf(c) <= 2.0f);
        const float f0 = fminf(fmaxf(floorf(a  + 2.0f), 0.0f), 3.0f);  // v_med3
        const float f1 = fminf(fmaxf(floorf(bb + 2.0f), 0.0f), 3.0f);
        const float f2 = fminf(fmaxf(floorf(c  + 2.0f), 0.0f), 3.0f);
        const int idx = (int)fmaf(f0, 16.0f, fmaf(f1, 4.0f, f2));      // exact small ints
        if (inside) atomicAdd(&h[idx], 1u);
    };

    const int stride = gridDim.x * TPB;
    for (int q = blockIdx.x * TPB + (int)threadIdx.x; q < Q; q += stride) {
        const floatx4 p0 = __builtin_nontemporal_load(&xq[3 * q + 0]);
        const floatx4 p1 = __builtin_nontemporal_load(&xq[3 * q + 1]);
        const floatx4 p2 = __builtin_nontemporal_load(&xq[3 * q + 2]);
        process(p0.x, p0.y, p0.z);
        process(p0.w, p1.x, p1.y);
        process(p1.z, p1.w, p2.x);
        process(p2.y, p2.z, p2.w);
    }

    // Tail points (N % 4 != 0): block x==0 only.
    if (blockIdx.x == 0) {
        for (int i = 4 * Q + (int)threadIdx.x; i < N; i += TPB) {
            process(xb[3 * i], xb[3 * i + 1], xb[3 * i + 2]);
        }
    }
    __syncthreads();

    if (threadIdx.x < 64) {
        // full overwrite of this block's slot (poison-safe, no init kernel)
        partials[((size_t)b * BPB + blockIdx.x) * 64 + threadIdx.x] = h[threadIdx.x];
    }
}

// Kernel 2: reduce partials + normalize + Linear(V=64 -> CLASSES=40).
// total in-range points per batch == sum of the 64 bins.
__global__ __launch_bounds__(64) void linear_kernel(const unsigned* __restrict__ partials,
                                                    const float* __restrict__ W,
                                                    const float* __restrict__ bias,
                                                    float* __restrict__ out) {
    const int b = blockIdx.x;
    const int v = threadIdx.x;

    unsigned s = 0u;
    #pragma unroll
    for (int p = 0; p < BPB; ++p)
        s += partials[((size_t)b * BPB + p) * 64 + v];   // coalesced across threads

    __shared__ float cnt[64];
    cnt[v] = (float)s;
    __syncthreads();

    const int c = v;
    if (c < 40) {
        float acc = 0.0f, tot = 0.0f;
        #pragma unroll
        for (int k = 0; k < 64; ++k) {
            const float cv = cnt[k];
            tot += cv;
            acc = fmaf(cv, W[c * 64 + k], acc);
        }
        out[b * 40 + c] = acc / tot + bias[c];
    }
}

extern "C" void kernel_launch(void* const* d_in, const int* in_sizes, int n_in,
                              void* d_out, int out_size, void* d_ws, size_t ws_size,
                              hipStream_t stream) {
    const float* x    = (const float*)d_in[0];   // [B, N, 3] fp32
    const float* W    = (const float*)d_in[1];   // [40, 64] fp32
    const float* bias = (const float*)d_in[2];   // [40] fp32
    float* out = (float*)d_out;                  // [64, 40] fp32

    const int B = 64;
    const int N = in_sizes[0] / (B * 3);         // 200000
    const int Q = N / 4;

    unsigned* partials = (unsigned*)d_ws;        // B*BPB*64 uint32 = 512 KB

    dim3 grid(BPB, B);
    hist_kernel<<<grid, TPB, 0, stream>>>(x, partials, Q, N);
    linear_kernel<<<B, 64, 0, stream>>>(partials, W, bias, out);
}